// Round 4
// baseline (476.650 us; speedup 1.0000x reference)
//
#include <hip/hip_runtime.h>
#include <type_traits>

// Problem constants: H=16, D=64, DM=1024, L=256, B=64, CHUNK=64, SCALE=1/8.

typedef short v8s __attribute__((ext_vector_type(8)));
typedef float v4f __attribute__((ext_vector_type(4)));

__device__ __forceinline__ float bf2f(short s) {
    unsigned int u = ((unsigned int)(unsigned short)s) << 16;
    float f;
    __builtin_memcpy(&f, &u, 4);
    return f;
}
__device__ __forceinline__ short f2bf(float f) {
    unsigned int u;
    __builtin_memcpy(&u, &f, 4);
    u = u + 0x7fffu + ((u >> 16) & 1u);   // RNE
    return (short)(u >> 16);
}

// async global->LDS, 16B per lane; LDS dest = wave-uniform base + lane*16
__device__ __forceinline__ void load_lds16(const short* g, short* l) {
    __builtin_amdgcn_global_load_lds((const __attribute__((address_space(1))) void*)g,
                                     (__attribute__((address_space(3))) void*)l, 16, 0, 0);
}

// ---------------- fp32 -> bf16 conversion (vectorized x4) ----------------
__global__ void __launch_bounds__(256)
cvt_bf16(const float* __restrict__ in, short* __restrict__ out, int n4) {
    int i = blockIdx.x * 256 + threadIdx.x;
    if (i >= n4) return;
    float4 v = ((const float4*)in)[i];
    short4 o;
    o.x = f2bf(v.x); o.y = f2bf(v.y); o.z = f2bf(v.z); o.w = f2bf(v.w);
    ((short4*)out)[i] = o;
}

// ---------------- bf16 MFMA GEMM:  C[M,N] = A[M,K] * B[N,K]^T ----------------
// BK=64 (half the barriers of m97's BK=32), XOR-swizzled LDS granules
// (swizzle applied to the GLOBAL source col per lane since global_load_lds
// dest is lane-linear; fragment reads add a loop-invariant ^(lr&7)).
// PHI: fold phi (elu+1, row-normalize over the 64-col segment) into the
// epilogue for q/k1/k2 segments; v segment stored plain.
template <typename OutT, bool PHI>
__global__ void __launch_bounds__(256)
gemm_nt(const short* __restrict__ A, const short* __restrict__ B,
        OutT* __restrict__ C, int M, int N, int K) {
    constexpr int BM = 128, BK = 64;
    __shared__ __align__(16) short sA[BM * BK];
    __shared__ __align__(16) short sB[BM * BK];
    const int tid = threadIdx.x;
    const int bm = blockIdx.x, bn = blockIdx.y;
    const int lane = tid & 63, w = tid >> 6;
    const int wy = w >> 1, wx = w & 1;
    const int lr = lane & 15, lq = lane >> 4;

    v4f acc[4][4] = {};

    // staging: wave w stages rows [32w,32w+32): 4 issues of 8 rows each.
    // lane -> row 32w+8j+(lane>>3), granule (lane&7)^(row&7) (8 shorts).
    const int sr = lane >> 3;
    const int sg = (lane & 7) ^ sr;
    const short* gA0 = A + (long)(bm * BM + 32 * w + sr) * K + sg * 8;
    const short* gB0 = B + (long)(bn * BM + 32 * w + sr) * K + sg * 8;
    short* lA0 = sA + 32 * w * BK;
    short* lB0 = sB + 32 * w * BK;

    // loop-invariant fragment addresses (logical granule half*4+lq, ^row&7)
    const short* fA[2][4];
    const short* fB[2][4];
#pragma unroll
    for (int half = 0; half < 2; half++)
#pragma unroll
        for (int i = 0; i < 4; i++) {
            int rowA = wy * 64 + i * 16 + lr;
            int rowB = wx * 64 + i * 16 + lr;
            fA[half][i] = &sA[rowA * BK + (((half * 4 + lq) ^ (lr & 7)) * 8)];
            fB[half][i] = &sB[rowB * BK + (((half * 4 + lq) ^ (lr & 7)) * 8)];
        }

    for (int kt = 0; kt < K; kt += BK) {
        __syncthreads();
#pragma unroll
        for (int j = 0; j < 4; j++) load_lds16(gA0 + 8 * j * K + kt, lA0 + 8 * j * BK);
#pragma unroll
        for (int j = 0; j < 4; j++) load_lds16(gB0 + 8 * j * K + kt, lB0 + 8 * j * BK);
        __syncthreads();
#pragma unroll
        for (int half = 0; half < 2; half++) {
            v8s af[4], bfv[4];
#pragma unroll
            for (int i = 0; i < 4; i++) af[i] = *(const v8s*)fA[half][i];
#pragma unroll
            for (int j = 0; j < 4; j++) bfv[j] = *(const v8s*)fB[half][j];
#pragma unroll
            for (int i = 0; i < 4; i++)
#pragma unroll
                for (int j = 0; j < 4; j++)
                    acc[i][j] = __builtin_amdgcn_mfma_f32_16x16x32_bf16(af[i], bfv[j], acc[i][j], 0, 0, 0);
        }
    }

    const bool dophi = PHI && (((bn * 2 + wx) & 3) < 3);   // wave-uniform
#pragma unroll
    for (int i = 0; i < 4; i++)
#pragma unroll
        for (int r = 0; r < 4; r++) {
            float vv[4];
#pragma unroll
            for (int j = 0; j < 4; j++) vv[j] = acc[i][j][r];
            if constexpr (PHI) {
                if (dophi) {
                    float s = 0.f;
#pragma unroll
                    for (int j = 0; j < 4; j++) {
                        float x = vv[j];
                        float e = x > 0.f ? x + 1.f : __expf(x);
                        vv[j] = e; s += e;
                    }
                    s += __shfl_xor(s, 1, 64);
                    s += __shfl_xor(s, 2, 64);
                    s += __shfl_xor(s, 4, 64);
                    s += __shfl_xor(s, 8, 64);
                    float inv = 1.f / s;
#pragma unroll
                    for (int j = 0; j < 4; j++) vv[j] *= inv;
                }
            }
            int row = bm * BM + wy * 64 + i * 16 + lq * 4 + r;
#pragma unroll
            for (int j = 0; j < 4; j++) {
                int col = bn * BM + wx * 64 + j * 16 + lr;
                if constexpr (std::is_same_v<OutT, short>)
                    C[(long)row * N + col] = f2bf(vv[j]);
                else
                    C[(long)row * N + col] = vv[j];
            }
        }
}

// ---------------- fast-weight scan (MFMA bf16; phi pre-applied) ----------------
#define SW(row, s) ((row) * 72 + ((((s) >> 3) ^ (((row) >> 4) & 7)) << 3) + ((s) & 7))

__global__ void __launch_bounds__(256)
fastweight(const short* __restrict__ qkv, short* __restrict__ out1, short* __restrict__ out2) {
    const int bid = blockIdx.x;
    const int mem = bid & 1, h = (bid >> 1) & 15, b = bid >> 5;
    const int tid = threadIdx.x;
    const int w = tid >> 6, lane = tid & 63;
    const int lq = lane >> 4, lr = lane & 15;
    __shared__ __align__(16) short sq[64 * 72];
    __shared__ __align__(16) short skS[64 * 72];   // k rows, then S overwrites
    __shared__ __align__(16) short skT[64 * 72];
    __shared__ __align__(16) short svT[64 * 72];
    __shared__ __align__(16) short sWT[64 * 72];
    short* outbuf = mem ? out2 : out1;
    const int koff = 64 + mem * 64;

    for (int i = tid; i < 64 * 36; i += 256) ((int*)sWT)[i] = 0;

    const int r = tid >> 2, seg = (tid & 3) * 16;

    v4f wacc[4] = {};   // persistent W^T slice

    for (int c = 0; c < 4; c++) {
        __syncthreads();
        const long gbase = ((long)((c * 64 + r) * 64 + b)) * 4096 + h * 256;
        {   // q (already phi'd): row-major
            int4 q0 = *(const int4*)(qkv + gbase + seg);
            int4 q1 = *(const int4*)(qkv + gbase + seg + 8);
            *(int4*)&sq[SW(r, seg)] = q0;
            *(int4*)&sq[SW(r, seg + 8)] = q1;
        }
        {   // k (already phi'd): row-major + transposed
            union { int4 v[2]; short s[16]; } u;
            u.v[0] = *(const int4*)(qkv + gbase + koff + seg);
            u.v[1] = *(const int4*)(qkv + gbase + koff + seg + 8);
            *(int4*)&skS[SW(r, seg)] = u.v[0];
            *(int4*)&skS[SW(r, seg + 8)] = u.v[1];
#pragma unroll
            for (int i = 0; i < 16; i++) skT[SW(seg + i, r)] = u.s[i];
        }
        {   // v: transposed only
            union { int4 v[2]; short s[16]; } u;
            u.v[0] = *(const int4*)(qkv + gbase + 192 + seg);
            u.v[1] = *(const int4*)(qkv + gbase + 192 + seg + 8);
#pragma unroll
            for (int i = 0; i < 16; i++) svT[SW(seg + i, r)] = u.s[i];
        }
        __syncthreads();

        v8s qa0 = *(const v8s*)&sq[SW(16 * w + lr, lq * 8)];
        v8s qa1 = *(const v8s*)&sq[SW(16 * w + lr, 32 + lq * 8)];

        // ---- S = q k^T ----
        v4f sacc[4];
#pragma unroll
        for (int n = 0; n < 4; n++) {
            v8s b0 = *(const v8s*)&skS[SW(16 * n + lr, lq * 8)];
            v8s b1 = *(const v8s*)&skS[SW(16 * n + lr, 32 + lq * 8)];
            v4f t = {};
            t = __builtin_amdgcn_mfma_f32_16x16x32_bf16(qa0, b0, t, 0, 0, 0);
            t = __builtin_amdgcn_mfma_f32_16x16x32_bf16(qa1, b1, t, 0, 0, 0);
            sacc[n] = t;
        }
        __syncthreads();
#pragma unroll
        for (int n = 0; n < 4; n++)
#pragma unroll
            for (int rr = 0; rr < 4; rr++) {
                int t_ = 16 * w + lq * 4 + rr;
                int s_ = 16 * n + lr;
                skS[SW(t_, s_)] = f2bf(s_ <= t_ ? sacc[n][rr] : 0.f);
            }

        // ---- O = S v + q W ----
        v8s sa0 = *(const v8s*)&skS[SW(16 * w + lr, lq * 8)];
        v8s sa1 = *(const v8s*)&skS[SW(16 * w + lr, 32 + lq * 8)];
        v4f oacc[4];
#pragma unroll
        for (int n = 0; n < 4; n++) {
            v8s vb0 = *(const v8s*)&svT[SW(16 * n + lr, lq * 8)];
            v8s vb1 = *(const v8s*)&svT[SW(16 * n + lr, 32 + lq * 8)];
            v8s wb0 = *(const v8s*)&sWT[SW(16 * n + lr, lq * 8)];
            v8s wb1 = *(const v8s*)&sWT[SW(16 * n + lr, 32 + lq * 8)];
            v4f t = {};
            t = __builtin_amdgcn_mfma_f32_16x16x32_bf16(sa0, vb0, t, 0, 0, 0);
            t = __builtin_amdgcn_mfma_f32_16x16x32_bf16(sa1, vb1, t, 0, 0, 0);
            t = __builtin_amdgcn_mfma_f32_16x16x32_bf16(qa0, wb0, t, 0, 0, 0);
            t = __builtin_amdgcn_mfma_f32_16x16x32_bf16(qa1, wb1, t, 0, 0, 0);
            oacc[n] = t;
        }
#pragma unroll
        for (int n = 0; n < 4; n++)
#pragma unroll
            for (int rr = 0; rr < 4; rr++) {
                int t_ = 16 * w + lq * 4 + rr;
                long o = ((long)((c * 64 + t_) * 64 + b)) * 1024 + h * 64 + 16 * n + lr;
                outbuf[o] = f2bf(oacc[n][rr]);
            }

        if (c < 3) {
            __syncthreads();
            // ---- W^T += v^T k ----
            v8s va0 = *(const v8s*)&svT[SW(16 * w + lr, lq * 8)];
            v8s va1 = *(const v8s*)&svT[SW(16 * w + lr, 32 + lq * 8)];
#pragma unroll
            for (int n = 0; n < 4; n++) {
                v8s kb0 = *(const v8s*)&skT[SW(16 * n + lr, lq * 8)];
                v8s kb1 = *(const v8s*)&skT[SW(16 * n + lr, 32 + lq * 8)];
                wacc[n] = __builtin_amdgcn_mfma_f32_16x16x32_bf16(va0, kb0, wacc[n], 0, 0, 0);
                wacc[n] = __builtin_amdgcn_mfma_f32_16x16x32_bf16(va1, kb1, wacc[n], 0, 0, 0);
            }
#pragma unroll
            for (int n = 0; n < 4; n++)
#pragma unroll
                for (int rr = 0; rr < 4; rr++)
                    sWT[SW(16 * w + lq * 4 + rr, 16 * n + lr)] = f2bf(wacc[n][rr]);
        }
    }
}

// ---------------- pi0 mixture: lmix = SCALE*(p*l1 + (1-p)*l2), bf16 x8 ----------------
__global__ void __launch_bounds__(256)
mix_kernel(const short* __restrict__ l1, const short* __restrict__ l2,
           const float* __restrict__ pi0, short* __restrict__ outm) {
    long idx8 = ((long)blockIdx.x * 256 + threadIdx.x) * 8;
    int col = (int)(idx8 & 1023);
    int row = (int)(idx8 >> 10);
    int hh = col >> 6;
    int l = row >> 6;   // row = l*B + b, B=64
    float p = pi0[hh * 256 + l];
    p = fminf(fmaxf(p, 0.f), 1.f);
    float q = 1.f - p;
    union { int4 v; short s[8]; } ua, ub, uo;
    ua.v = *(const int4*)(l1 + idx8);
    ub.v = *(const int4*)(l2 + idx8);
#pragma unroll
    for (int i = 0; i < 8; i++)
        uo.s[i] = f2bf(0.125f * (p * bf2f(ua.s[i]) + q * bf2f(ub.s[i])));
    *(int4*)(outm + idx8) = uo.v;
}

// ---------------- residual + LayerNorm over DM=1024 ----------------
__global__ void __launch_bounds__(256)
ln_kernel(const float* __restrict__ h, const float* __restrict__ attn,
          const float* __restrict__ gamma, const float* __restrict__ beta,
          float* __restrict__ out) {
    const int row = blockIdx.x;
    const long base = (long)row * 1024;
    const int tid = threadIdx.x;
    float4 xh = ((const float4*)(h + base))[tid];
    float4 xa = ((const float4*)(attn + base))[tid];
    float4 x;
    x.x = xh.x + xa.x; x.y = xh.y + xa.y; x.z = xh.z + xa.z; x.w = xh.w + xa.w;
    float s = x.x + x.y + x.z + x.w;
    float s2 = x.x * x.x + x.y * x.y + x.z * x.z + x.w * x.w;
#pragma unroll
    for (int m = 32; m > 0; m >>= 1) {
        s += __shfl_xor(s, m, 64);
        s2 += __shfl_xor(s2, m, 64);
    }
    __shared__ float ps[4], ps2[4];
    int w = tid >> 6, lane = tid & 63;
    if (lane == 0) { ps[w] = s; ps2[w] = s2; }
    __syncthreads();
    s = ps[0] + ps[1] + ps[2] + ps[3];
    s2 = ps2[0] + ps2[1] + ps2[2] + ps2[3];
    float mu = s * (1.f / 1024.f);
    float var = s2 * (1.f / 1024.f) - mu * mu;
    float inv = rsqrtf(var + 1e-5f);
    float4 g = ((const float4*)gamma)[tid];
    float4 bb = ((const float4*)beta)[tid];
    float4 o;
    o.x = (x.x - mu) * inv * g.x + bb.x;
    o.y = (x.y - mu) * inv * g.y + bb.y;
    o.z = (x.z - mu) * inv * g.z + bb.z;
    o.w = (x.w - mu) * inv * g.w + bb.w;
    ((float4*)(out + base))[tid] = o;
}

extern "C" void kernel_launch(void* const* d_in, const int* in_sizes, int n_in,
                              void* d_out, int out_size, void* d_ws, size_t ws_size,
                              hipStream_t stream) {
    const float* h     = (const float*)d_in[0];
    const float* qkvw  = (const float*)d_in[1];
    const float* ow    = (const float*)d_in[2];
    const float* gamma = (const float*)d_in[3];
    const float* beta  = (const float*)d_in[4];
    const float* pi0   = (const float*)d_in[5];
    float* out = (float*)d_out;
    char* ws = (char*)d_ws;

    short* h_bf   = (short*)(ws);                 // 32MB; reused later as layer_mix
    short* wq_bf  = (short*)(ws + 33554432);      // 8MB
    short* wo_bf  = (short*)(ws + 41943040);      // 2MB
    short* qkv_bf = (short*)(ws + 44040192);      // 128MB; reused later as attn f32 (64MB)
    short* l1     = (short*)(ws + 178257920);     // 32MB
    short* l2     = (short*)(ws + 211812352);     // 32MB
    float* attnf  = (float*)(ws + 44040192);
    short* lmix   = h_bf;

    cvt_bf16<<<16384, 256, 0, stream>>>(h, h_bf, 16777216 / 4);
    cvt_bf16<<<4096, 256, 0, stream>>>(qkvw, wq_bf, 4194304 / 4);
    cvt_bf16<<<1024, 256, 0, stream>>>(ow, wo_bf, 1048576 / 4);

    // qkv = phi-fused h @ qkv_w^T : [16384, 4096]
    gemm_nt<short, true><<<dim3(128, 32), 256, 0, stream>>>(h_bf, wq_bf, qkv_bf, 16384, 4096, 1024);

    fastweight<<<2048, 256, 0, stream>>>(qkv_bf, l1, l2);

    mix_kernel<<<8192, 256, 0, stream>>>(l1, l2, pi0, lmix);

    gemm_nt<float, false><<<dim3(128, 8), 256, 0, stream>>>(lmix, wo_bf, attnf, 16384, 1024, 1024);

    ln_kernel<<<16384, 256, 0, stream>>>(h, attnf, gamma, beta, out);
}